// Round 6
// baseline (413.047 us; speedup 1.0000x reference)
//
#include <hip/hip_runtime.h>
#include <hip/hip_bf16.h>
#include <stdint.h>

// Problem constants (fixed by the reference): B=4, S=8192, IN=1024, OUT=1024
#define M_TOT  32768
#define K_DIM  1024
#define N_DIM  1024

typedef short bf16x8 __attribute__((ext_vector_type(8)));   // 8 bf16 = 4 VGPRs
typedef float f32x4  __attribute__((ext_vector_type(4)));

#define AS1(p) ((__attribute__((address_space(1))) void*)(p))
#define AS3(p) ((__attribute__((address_space(3))) void*)(p))

__device__ __forceinline__ uint32_t packbf2(float a, float b) {
    __hip_bfloat162 h = __float22bfloat162_rn(make_float2(a, b));
    union { __hip_bfloat162 h; uint32_t u; } cvt;
    cvt.h = h;
    return cvt.u;
}

// ---------- prep: compaction (32 blocks) + W fp32->bf16 (256 blocks), ONE launch ----------
// (verbatim R5 prep — measured cheap)
__global__ __launch_bounds__(1024) void prep_kernel(
        const int* __restrict__ mask,
        const float* __restrict__ wv, const float* __restrict__ wt,
        ushort* __restrict__ dv, ushort* __restrict__ dt,
        int* __restrict__ V, int* __restrict__ T, int* __restrict__ cnt) {
    const int b   = blockIdx.x;
    const int tid = threadIdx.x;

    if (b < 32) {
        const int lane = tid & 63;
        const int wv_i = tid >> 6;

        // (1) global V-prefix: popcount of mask[0, b*1024)
        int pre = 0;
        const int nPre4 = b * 256;                    // int4 count
        for (int i = tid; i < nPre4; i += 1024) {
            int4 v = ((const int4*)mask)[i];
            pre += (v.x != 0) + (v.y != 0) + (v.z != 0) + (v.w != 0);
        }
#pragma unroll
        for (int d = 32; d > 0; d >>= 1) pre += __shfl_down(pre, d);
        __shared__ int wsum[16];
        __shared__ int pref_s;
        if (lane == 0) wsum[wv_i] = pre;
        __syncthreads();
        if (tid == 0) {
            int s = 0;
#pragma unroll
            for (int i = 0; i < 16; ++i) s += wsum[i];
            pref_s = s;
        }
        __syncthreads();
        const int prefix_v = pref_s;

        // (2) own element: ballot-compact, one store per thread
        const int e   = b * 1024 + tid;
        const int bit = (mask[e] != 0) ? 1 : 0;
        unsigned long long bal = __ballot(bit);
        const int lexcl = __popcll(bal & ((1ull << lane) - 1ull));
        const int wcnt  = __popcll(bal);
        __shared__ int wc[16];
        if (lane == 0) wc[wv_i] = wcnt;
        __syncthreads();
        int wpre = 0;
        for (int i = 0; i < wv_i; ++i) wpre += wc[i];
        int chunk_tot = 0;
#pragma unroll
        for (int i = 0; i < 16; ++i) chunk_tot += wc[i];
        const int gv = prefix_v + wpre + lexcl;
        if (bit) V[gv]     = e;
        else     T[e - gv] = e;

        // (3) block 31: totals + sentinel padding
        if (b == 31) {
            const int Nv = prefix_v + chunk_tot;
            const int Nt = M_TOT - Nv;
            if (tid == 0) { cnt[0] = Nv; cnt[1] = Nt; }
            const int NBv = (Nv + 127) >> 7, NBt = (Nt + 127) >> 7;
            for (int p = Nv + tid; p < NBv * 128; p += 1024) V[p] = -1;
            for (int p = Nt + tid; p < NBt * 128; p += 1024) T[p] = -1;
        }
        return;
    }

    // ---- W fp32 -> bf16 ----
    int u = (b - 32) * 8192 + tid * 8;
    const float* src; ushort* dst; int off;
    if (u < 1048576) { src = wv; dst = dv; off = u; }
    else             { src = wt; dst = dt; off = u - 1048576; }
    float4 a0 = *(const float4*)(src + off);
    float4 a1 = *(const float4*)(src + off + 4);
    uint4 p;
    p.x = packbf2(a0.x, a0.y);
    p.y = packbf2(a0.z, a0.w);
    p.z = packbf2(a1.x, a1.y);
    p.w = packbf2(a1.z, a1.w);
    *(uint4*)(dst + off) = p;
}

// ---------- gathered-row 128x128x(BK=32) GEMM, fp32-A DMA, 2-phase dbuf ----------
// Both tiles double-buffered (48 KB -> 3 blocks/CU).  Per K-step:
//   STAGE(t+1 -> buf[nxt])  (async gload_lds, flies under compute)
//   frag-read buf[cur] (+fused fp32->bf16 cvt for A), 16 MFMA
//   __syncthreads()          (vmcnt drain AFTER compute phase)
// No inline asm; compiler owns all waitcnts.
__global__ __launch_bounds__(256) void gemm_kernel(
        const float*  __restrict__ x,
        const ushort* __restrict__ Wv,
        const ushort* __restrict__ Wt,
        const int*    __restrict__ V,
        const int*    __restrict__ T,
        const int*    __restrict__ cnt,
        float*        __restrict__ out) {
    // A: fp32 chunk(4 f32) (row,kc) at chunk idx row*8 + (kc ^ (row&7)), kc in [0,8)
    // B: bf16 chunk(8 bf16) (row,kc) at chunk idx row*4 + (kc ^ (row&3)), kc in [0,4)
    __shared__ float  sA[2][128 * 32];   // 2 x 16 KB
    __shared__ ushort sB[2][128 * 32];   // 2 x 8 KB

    const int tid  = threadIdx.x;
    const int lane = tid & 63;
    const int w    = tid >> 6;

    // XCD-sticky swizzle: all 8 bn-blocks of one bm share blockIdx%8
    const int kx = blockIdx.x & 7;
    const int bn = (blockIdx.x >> 3) & 7;
    const int gk = blockIdx.x >> 6;
    const int bm = gk * 8 + kx;

    const int Nv  = cnt[0];
    const int Nt  = cnt[1];
    const int NBv = (Nv + 127) >> 7;
    const int NBt = (Nt + 127) >> 7;
    if (bm >= NBv + NBt) return;

    const bool vis = (bm < NBv);
    const int*    rowbase = vis ? (V + (size_t)bm * 128)
                                : (T + (size_t)(bm - NBv) * 128);
    const ushort* W       = vis ? Wv : Wt;
    const int n0 = bn * 128;

    // ---- A DMA: thread covers chunks p = r*256+tid, r=0..3 ->
    //      row = r*32 + (tid>>3), kc = (tid&7) ^ ((tid>>3)&7)   (16B fp32 chunks)
    const int arow = tid >> 3;
    const int akc  = (tid & 7) ^ (arow & 7);
    const float* ap[4];
#pragma unroll
    for (int r = 0; r < 4; ++r) {
        int rr = rowbase[r * 32 + arow];
        if (rr < 0) rr = 0;                      // sentinel: safe addr, masked at store
        ap[r] = x + (size_t)rr * K_DIM + akc * 4;
    }
    // ---- B DMA: thread covers chunks p = r*256+tid, r=0..1 ->
    //      row = r*64 + (tid>>2), kc = (tid&3) ^ ((tid>>2)&3)   (16B bf16 chunks)
    const int brow = tid >> 2;
    const int bkc  = (tid & 3) ^ (brow & 3);
    const ushort* wp[2];
#pragma unroll
    for (int r = 0; r < 2; ++r) {
        wp[r] = W + (size_t)(n0 + r * 64 + brow) * K_DIM + bkc * 8;
    }

    // fragment read offsets (bytes, within one buffer)
    const int ml   = lane & 15;
    const int quad = lane >> 4;
    const int wm = (w & 1) * 64;
    const int wn = (w >> 1) * 64;
    uint32_t aoff[4], boff[4];
#pragma unroll
    for (int t = 0; t < 4; ++t) {
        const int am = wm + t * 16 + ml;                 // A row
        const int an = wn + t * 16 + ml;                 // B row
        aoff[t] = (uint32_t)((am * 8 + ((2 * quad) ^ (am & 7))) * 16);
        boff[t] = (uint32_t)((an * 4 + (quad ^ (an & 3))) * 16);
    }

    f32x4 acc[4][4];
#pragma unroll
    for (int i = 0; i < 4; ++i)
#pragma unroll
        for (int j = 0; j < 4; ++j) {
            f32x4 z = {0.f, 0.f, 0.f, 0.f};
            acc[i][j] = z;
        }

    char* sA0 = (char*)sA[0];
    char* sA1 = (char*)sA[1];
    char* sB0 = (char*)sB[0];
    char* sB1 = (char*)sB[1];

    // stage tile T into buffer (base pair): 4 A-chunks + 2 B-chunks, async DMA
#define STAGE(SAB, SBB, T)                                                      \
    {                                                                           \
        const int kA = (T) * 32;                                                \
        _Pragma("unroll")                                                       \
        for (int r = 0; r < 4; ++r) {                                           \
            char* la = (SAB) + (size_t)(r * 256 + tid) * 16;                    \
            __builtin_amdgcn_global_load_lds(AS1(ap[r] + kA), AS3(la), 16, 0, 0);\
        }                                                                       \
        _Pragma("unroll")                                                       \
        for (int r = 0; r < 2; ++r) {                                           \
            char* lb = (SBB) + (size_t)(r * 256 + tid) * 16;                    \
            __builtin_amdgcn_global_load_lds(AS1(wp[r] + kA), AS3(lb), 16, 0, 0);\
        }                                                                       \
    }

    // compute tile from buffer: frag reads + fused cvt + 16 MFMA
#define COMPUTE(SAB, SBB)                                                       \
    {                                                                           \
        bf16x8 af[4], bf[4];                                                    \
        _Pragma("unroll")                                                       \
        for (int t = 0; t < 4; ++t) {                                           \
            f32x4 lo = *(const f32x4*)((SAB) + aoff[t]);                        \
            f32x4 hi = *(const f32x4*)((SAB) + (aoff[t] ^ 16u));                \
            union { uint32_t u[4]; bf16x8 v; } cv;                              \
            cv.u[0] = packbf2(lo[0], lo[1]);                                    \
            cv.u[1] = packbf2(lo[2], lo[3]);                                    \
            cv.u[2] = packbf2(hi[0], hi[1]);                                    \
            cv.u[3] = packbf2(hi[2], hi[3]);                                    \
            af[t] = cv.v;                                                       \
        }                                                                       \
        _Pragma("unroll")                                                       \
        for (int t = 0; t < 4; ++t) bf[t] = *(const bf16x8*)((SBB) + boff[t]);  \
        _Pragma("unroll")                                                       \
        for (int tm = 0; tm < 4; ++tm)                                          \
            _Pragma("unroll")                                                   \
            for (int tn = 0; tn < 4; ++tn)                                      \
                acc[tm][tn] = __builtin_amdgcn_mfma_f32_16x16x32_bf16(          \
                    af[tm], bf[tn], acc[tm][tn], 0, 0, 0);                      \
    }

    // prologue: tile 0 -> buf0
    STAGE(sA0, sB0, 0);
    __syncthreads();

    for (int tt = 0; tt < 32; tt += 2) {
        // step tt: compute buf0, stage tt+1 -> buf1
        STAGE(sA1, sB1, tt + 1);
        COMPUTE(sA0, sB0);
        __syncthreads();
        // step tt+1: compute buf1, stage tt+2 -> buf0
        if (tt + 2 < 32) STAGE(sA0, sB0, tt + 2);
        COMPUTE(sA1, sB1);
        __syncthreads();
    }
#undef STAGE
#undef COMPUTE

    // epilogue: scatter rows via index list (C/D: col=lane&15, row=quad*4+reg)
#pragma unroll
    for (int tm = 0; tm < 4; ++tm) {
        const int rb = wm + tm * 16 + quad * 4;
        int sr0 = rowbase[rb + 0];
        int sr1 = rowbase[rb + 1];
        int sr2 = rowbase[rb + 2];
        int sr3 = rowbase[rb + 3];
#pragma unroll
        for (int tn = 0; tn < 4; ++tn) {
            const int col = n0 + wn + tn * 16 + ml;
            if (sr0 >= 0) out[(size_t)sr0 * N_DIM + col] = acc[tm][tn][0];
            if (sr1 >= 0) out[(size_t)sr1 * N_DIM + col] = acc[tm][tn][1];
            if (sr2 >= 0) out[(size_t)sr2 * N_DIM + col] = acc[tm][tn][2];
            if (sr3 >= 0) out[(size_t)sr3 * N_DIM + col] = acc[tm][tn][3];
        }
    }
}

// ws layout:
//   [0, 2MB)        W_v bf16
//   [2MB, 4MB)      W_t bf16
//   [4MB, +128KB)   V index list (32768 int)
//   [...,+128KB)    T index list (32768 int)
//   [...,+8B)       counters {Nv, Nt}
extern "C" void kernel_launch(void* const* d_in, const int* in_sizes, int n_in,
                              void* d_out, int out_size, void* d_ws, size_t ws_size,
                              hipStream_t stream) {
    const float* x    = (const float*)d_in[0];
    const int*   mask = (const int*)d_in[1];
    const float* Wv   = (const float*)d_in[2];
    const float* Wt   = (const float*)d_in[3];
    float* out = (float*)d_out;

    char* ws = (char*)d_ws;
    ushort* dWv = (ushort*)(ws);
    ushort* dWt = (ushort*)(ws + (1 << 21));
    int* V   = (int*)(ws + (1 << 22));
    int* T   = V + 32768;
    int* cnt = T + 32768;

    prep_kernel<<<288, 1024, 0, stream>>>(mask, Wv, Wt, dWv, dWt, V, T, cnt);
    // grid: bm = gk*8 + (blockIdx&7) must reach ~258 -> gk up to 32 -> 33*64 blocks
    gemm_kernel<<<33 * 64, 256, 0, stream>>>(x, dWv, dWt, V, T, cnt, out);
}

// Round 7
// 324.060 us; speedup vs baseline: 1.2746x; 1.2746x over previous
//
#include <hip/hip_runtime.h>
#include <hip/hip_bf16.h>
#include <stdint.h>

// Problem constants (fixed by the reference): B=4, S=8192, IN=1024, OUT=1024
#define M_TOT  32768
#define K_DIM  1024
#define N_DIM  1024

typedef short bf16x8 __attribute__((ext_vector_type(8)));   // 8 bf16 = 4 VGPRs
typedef float f32x4  __attribute__((ext_vector_type(4)));

#define AS1(p) ((__attribute__((address_space(1))) void*)(p))
#define AS3(p) ((__attribute__((address_space(3))) void*)(p))

__device__ __forceinline__ uint32_t packbf2(float a, float b) {
    __hip_bfloat162 h = __float22bfloat162_rn(make_float2(a, b));
    union { __hip_bfloat162 h; uint32_t u; } cvt;
    cvt.h = h;
    return cvt.u;
}

// ---------- prep: ONE launch: compaction (32) + W cvt (256) + x cvt (4096) ----------
// (R4 prep, proven; lists now padded to 256-row tiles)
__global__ __launch_bounds__(1024) void prep_kernel(
        const float* __restrict__ x,  const int* __restrict__ mask,
        const float* __restrict__ wv, const float* __restrict__ wt,
        ushort* __restrict__ xb, ushort* __restrict__ dv, ushort* __restrict__ dt,
        int* __restrict__ V, int* __restrict__ T, int* __restrict__ cnt) {
    const int b   = blockIdx.x;
    const int tid = threadIdx.x;

    if (b < 32) {
        // ---- compaction: block b owns elements [b*1024, (b+1)*1024) ----
        const int lane = tid & 63;
        const int wv_i = tid >> 6;

        // (1) global V-prefix: popcount of mask[0, b*1024)
        int pre = 0;
        const int nPre4 = b * 256;                    // int4 count
        for (int i = tid; i < nPre4; i += 1024) {
            int4 v = ((const int4*)mask)[i];
            pre += (v.x != 0) + (v.y != 0) + (v.z != 0) + (v.w != 0);
        }
#pragma unroll
        for (int d = 32; d > 0; d >>= 1) pre += __shfl_down(pre, d);
        __shared__ int wsum[16];
        __shared__ int pref_s;
        if (lane == 0) wsum[wv_i] = pre;
        __syncthreads();
        if (tid == 0) {
            int s = 0;
#pragma unroll
            for (int i = 0; i < 16; ++i) s += wsum[i];
            pref_s = s;
        }
        __syncthreads();
        const int prefix_v = pref_s;

        // (2) own element: ballot-compact, one store per thread
        const int e   = b * 1024 + tid;
        const int bit = (mask[e] != 0) ? 1 : 0;
        unsigned long long bal = __ballot(bit);
        const int lexcl = __popcll(bal & ((1ull << lane) - 1ull));
        const int wcnt  = __popcll(bal);
        __shared__ int wc[16];
        if (lane == 0) wc[wv_i] = wcnt;
        __syncthreads();
        int wpre = 0;
        for (int i = 0; i < wv_i; ++i) wpre += wc[i];
        int chunk_tot = 0;
#pragma unroll
        for (int i = 0; i < 16; ++i) chunk_tot += wc[i];
        const int gv = prefix_v + wpre + lexcl;      // V's strictly before e
        if (bit) V[gv]     = e;
        else     T[e - gv] = e;

        // (3) block 31: totals + sentinel padding to 256-row tiles
        if (b == 31) {
            const int Nv = prefix_v + chunk_tot;
            const int Nt = M_TOT - Nv;
            if (tid == 0) { cnt[0] = Nv; cnt[1] = Nt; }
            const int NBv = (Nv + 255) >> 8, NBt = (Nt + 255) >> 8;
            for (int p = Nv + tid; p < NBv * 256; p += 1024) V[p] = -1;
            for (int p = Nt + tid; p < NBt * 256; p += 1024) T[p] = -1;
        }
        return;
    }

    if (b < 288) {
        // ---- W fp32 -> bf16: 2*1024*1024 elems over 256 blocks x 1024 thr x 8 ----
        int u = (b - 32) * 8192 + tid * 8;
        const float* src; ushort* dst; int off;
        if (u < 1048576) { src = wv; dst = dv; off = u; }
        else             { src = wt; dst = dt; off = u - 1048576; }
        float4 a0 = *(const float4*)(src + off);
        float4 a1 = *(const float4*)(src + off + 4);
        uint4 p;
        p.x = packbf2(a0.x, a0.y);
        p.y = packbf2(a0.z, a0.w);
        p.z = packbf2(a1.x, a1.y);
        p.w = packbf2(a1.z, a1.w);
        *(uint4*)(dst + off) = p;
        return;
    }

    // ---- x fp32 -> bf16: 33554432 elems over 4096 blocks x 1024 thr x 8 ----
    const int off = (b - 288) * 8192 + tid * 8;
    float4 a0 = *(const float4*)(x + off);
    float4 a1 = *(const float4*)(x + off + 4);
    uint4 p;
    p.x = packbf2(a0.x, a0.y);
    p.y = packbf2(a0.z, a0.w);
    p.z = packbf2(a1.x, a1.y);
    p.w = packbf2(a1.z, a1.w);
    *(uint4*)(xb + off) = p;
}

// ---------- gathered-row 256x256x(BK=64) bf16 MFMA GEMM, counted-vmcnt pipeline ----------
// 512 threads (8 waves, 2M x 4N), 128 KB LDS (both tiles double-buffered).
// Per K-step: STAGE(t+1 -> nxt buf) [8 DMA/thread], s_waitcnt vmcnt(8) (drains
// tile t only; t+1's 8 stay in flight across BOTH barriers), barrier,
// 64 MFMA from cur buf, barrier.  vmcnt never 0 in the main loop (T4).
// LDS layout (proven 0-conflict family): chunk (row,kc) at index row*8 + (kc^(row&7)),
// row stride 128 B; DMA dest linear, source pre-swizzled per-lane.
__global__ __launch_bounds__(512, 2) void gemm_kernel(
        const ushort* __restrict__ xb,
        const ushort* __restrict__ Wv,
        const ushort* __restrict__ Wt,
        const int*    __restrict__ V,
        const int*    __restrict__ T,
        const int*    __restrict__ cnt,
        float*        __restrict__ out) {
    __shared__ ushort sA[2][256 * 64];   // 2 x 32 KB
    __shared__ ushort sB[2][256 * 64];   // 2 x 32 KB

    const int tid  = threadIdx.x;
    const int lane = tid & 63;
    const int w    = tid >> 6;

    // XCD-sticky: all 4 bn-blocks of one bm share bid&7 (same XCD -> A-panel L2 reuse)
    const int bid = blockIdx.x;
    const int bm  = (bid & 7) + 8 * (bid >> 5);
    const int bn  = (bid >> 3) & 3;

    const int Nv  = cnt[0];
    const int Nt  = cnt[1];
    const int NBv = (Nv + 255) >> 8;
    const int NBt = (Nt + 255) >> 8;
    if (bm >= NBv + NBt) return;

    const bool vis = (bm < NBv);
    const int*    rowbase = vis ? (V + (size_t)bm * 256)
                                : (T + (size_t)(bm - NBv) * 256);
    const ushort* W       = vis ? Wv : Wt;
    const int n0 = bn * 256;

    // DMA staging: thread covers chunks p = r*512 + tid (r=0..3) of each tile ->
    //   row = r*64 + (tid>>3), kc = (tid&7) ^ ((tid>>3)&7)   (16B bf16 chunks)
    const int trow = tid >> 3;
    const int kcb  = (tid & 7) ^ (trow & 7);
    const ushort* ap[4];
    const ushort* wp[4];
#pragma unroll
    for (int r = 0; r < 4; ++r) {
        int rr = rowbase[r * 64 + trow];
        if (rr < 0) rr = 0;                      // sentinel row: safe addr, masked at store
        ap[r] = xb + (size_t)rr * K_DIM + kcb * 8;
        wp[r] = W + (size_t)(n0 + r * 64 + trow) * K_DIM + kcb * 8;
    }

    // fragment read offsets (bytes, ks=0; ks=1 is ^64)
    const int ml   = lane & 15;
    const int quad = lane >> 4;
    const int wr = w >> 2;                 // 0..1  -> M offset wr*128
    const int wc = w & 3;                  // 0..3  -> N offset wc*64
    uint32_t aoff[8], boff[4];
#pragma unroll
    for (int t = 0; t < 8; ++t) {
        const int am = wr * 128 + t * 16 + ml;
        aoff[t] = (uint32_t)((am * 8 + (quad ^ (ml & 7))) * 16);
    }
#pragma unroll
    for (int t = 0; t < 4; ++t) {
        const int an = wc * 64 + t * 16 + ml;
        boff[t] = (uint32_t)((an * 8 + (quad ^ (ml & 7))) * 16);
    }

    f32x4 acc[8][4];
#pragma unroll
    for (int i = 0; i < 8; ++i)
#pragma unroll
        for (int j = 0; j < 4; ++j) {
            f32x4 z = {0.f, 0.f, 0.f, 0.f};
            acc[i][j] = z;
        }

    char* a0 = (char*)sA[0];
    char* a1 = (char*)sA[1];
    char* b0 = (char*)sB[0];
    char* b1 = (char*)sB[1];

#define STAGE(AB, BB, T_)                                                         \
    {                                                                             \
        const int kk = (T_) * 64;                                                 \
        _Pragma("unroll")                                                         \
        for (int r = 0; r < 4; ++r) {                                             \
            char* la = (AB) + (size_t)(r * 512 + w * 64) * 16;                    \
            __builtin_amdgcn_global_load_lds(AS1(ap[r] + kk), AS3(la), 16, 0, 0); \
        }                                                                         \
        _Pragma("unroll")                                                         \
        for (int r = 0; r < 4; ++r) {                                             \
            char* lb = (BB) + (size_t)(r * 512 + w * 64) * 16;                    \
            __builtin_amdgcn_global_load_lds(AS1(wp[r] + kk), AS3(lb), 16, 0, 0); \
        }                                                                         \
    }

#define COMPUTE(AB, BB)                                                           \
    {                                                                             \
        _Pragma("unroll")                                                         \
        for (int ksb = 0; ksb < 2; ++ksb) {                                       \
            const uint32_t kx_ = (uint32_t)(ksb * 64);                            \
            bf16x8 af[8], bf[4];                                                  \
            _Pragma("unroll")                                                     \
            for (int t = 0; t < 8; ++t) af[t] = *(const bf16x8*)((AB) + (aoff[t] ^ kx_)); \
            _Pragma("unroll")                                                     \
            for (int t = 0; t < 4; ++t) bf[t] = *(const bf16x8*)((BB) + (boff[t] ^ kx_)); \
            _Pragma("unroll")                                                     \
            for (int tm = 0; tm < 8; ++tm)                                        \
                _Pragma("unroll")                                                 \
                for (int tn = 0; tn < 4; ++tn)                                    \
                    acc[tm][tn] = __builtin_amdgcn_mfma_f32_16x16x32_bf16(        \
                        af[tm], bf[tn], acc[tm][tn], 0, 0, 0);                    \
        }                                                                         \
    }

#define WAIT8 asm volatile("s_waitcnt vmcnt(8)" ::: "memory")
#define WAIT0 asm volatile("s_waitcnt vmcnt(0)" ::: "memory")
#define BAR   do { asm volatile("" ::: "memory"); __builtin_amdgcn_s_barrier(); \
                   asm volatile("" ::: "memory"); } while (0)

    // drain all prologue vmem so vmcnt counts only our DMAs
    WAIT0;
    STAGE(a0, b0, 0);

    for (int it = 0; it < 7; ++it) {            // kt = 0..13
        const int t0 = it * 2;
        STAGE(a1, b1, t0 + 1); WAIT8; BAR; COMPUTE(a0, b0); BAR;
        STAGE(a0, b0, t0 + 2); WAIT8; BAR; COMPUTE(a1, b1); BAR;
    }
    // kt = 14
    STAGE(a1, b1, 15); WAIT8; BAR; COMPUTE(a0, b0); BAR;
    // kt = 15
    WAIT0; BAR; COMPUTE(a1, b1);

#undef STAGE
#undef COMPUTE
#undef WAIT8
#undef WAIT0
#undef BAR

    // epilogue: scatter rows via index list (C/D: col=lane&15, row=quad*4+reg)
#pragma unroll
    for (int tm = 0; tm < 8; ++tm) {
        const int rb = wr * 128 + tm * 16 + quad * 4;
        int sr0 = rowbase[rb + 0];
        int sr1 = rowbase[rb + 1];
        int sr2 = rowbase[rb + 2];
        int sr3 = rowbase[rb + 3];
#pragma unroll
        for (int tn = 0; tn < 4; ++tn) {
            const int col = n0 + wc * 64 + tn * 16 + ml;
            if (sr0 >= 0) out[(size_t)sr0 * N_DIM + col] = acc[tm][tn][0];
            if (sr1 >= 0) out[(size_t)sr1 * N_DIM + col] = acc[tm][tn][1];
            if (sr2 >= 0) out[(size_t)sr2 * N_DIM + col] = acc[tm][tn][2];
            if (sr3 >= 0) out[(size_t)sr3 * N_DIM + col] = acc[tm][tn][3];
        }
    }
}

// ws layout:
//   [0, 64MB)            x bf16 (32768 x 1024)
//   [64MB, 66MB)         W_v bf16
//   [66MB, 68MB)         W_t bf16
//   [68MB, +132096B)     V index list (33024 int, 256-padded)
//   [.., +132096B)       T index list (33024 int, 256-padded)
//   [.., +8B)            counters {Nv, Nt}
extern "C" void kernel_launch(void* const* d_in, const int* in_sizes, int n_in,
                              void* d_out, int out_size, void* d_ws, size_t ws_size,
                              hipStream_t stream) {
    const float* x    = (const float*)d_in[0];
    const int*   mask = (const int*)d_in[1];
    const float* Wv   = (const float*)d_in[2];
    const float* Wt   = (const float*)d_in[3];
    float* out = (float*)d_out;

    char* ws = (char*)d_ws;
    ushort* xb  = (ushort*)(ws);
    ushort* dWv = (ushort*)(ws + 67108864);
    ushort* dWt = (ushort*)(ws + 69206016);
    int* V   = (int*)(ws + 71303168);
    int* T   = (int*)(ws + 71303168 + 132096);
    int* cnt = (int*)(ws + 71303168 + 2 * 132096);

    prep_kernel<<<4384, 1024, 0, stream>>>(x, mask, Wv, Wt, xb, dWv, dWt, V, T, cnt);
    // grid: bm = (bid&7) + 8*(bid>>5) up to ~129 -> 17*32 = 544 blocks; bn = (bid>>3)&3
    gemm_kernel<<<544, 512, 0, stream>>>(xb, dWv, dWt, V, T, cnt, out);
}